// Round 1
// baseline (518.685 us; speedup 1.0000x reference)
//
#include <hip/hip_runtime.h>
#include <math.h>

#define Dk 1024
#define Hk 256
#define Lk 8192
#define Bk 8
#define MTOT (Bk*Lk)   // 65536 rows

// ---------------- prep: S[j] = sum_d gamma[d]*W1[d][j], Tb[j] = sum_d beta[d]*W1[d][j] + b1[j]
__global__ __launch_bounds__(256) void prep_kernel(
    const float* __restrict__ gamma, const float* __restrict__ beta,
    const float* __restrict__ W1, const float* __restrict__ b1,
    float* __restrict__ S, float* __restrict__ Tb) {
  int j = threadIdx.x;  // 0..255
  float s = 0.f, t = 0.f;
  for (int d = 0; d < Dk; ++d) {
    float w = W1[d * Hk + j];
    s = fmaf(gamma[d], w, s);
    t = fmaf(beta[d], w, t);
  }
  S[j] = s;
  Tb[j] = t + b1[j];
}

// ---------------- scores: fused LN + Linear(1024->256) + GELU + Linear(256->1)
// GEMM on RAW features (gamma applied at staging, LN affine folded into epilogue):
//   hpre[r][j] = rs_r * acc[r][j] - rs_r*mu_r*S[j] + Tb[j]
// Row stats accumulated during A staging (single pass over features).
__global__ __launch_bounds__(512) void scores_kernel(
    const float* __restrict__ F, const float* __restrict__ gamma,
    const float* __restrict__ W1,
    const float* __restrict__ S, const float* __restrict__ Tb,
    const float* __restrict__ W2, const float* __restrict__ b2,
    float* __restrict__ scores_out) {
  __shared__ float As[16][132];   // k-major, +4 pad: staging writes 2-way (free)
  __shared__ float Bs[16][256];
  __shared__ float smu[128];
  __shared__ float srs[128];

  const int tid = threadIdx.x;
  const int tx = tid & 31;        // n dimension (32 lanes)
  const int ty = tid >> 5;        // m dimension (16)
  const int RM = blockIdx.x * 128;

  // staging indices
  const int ar  = tid >> 2;        // A row 0..127
  const int akq = (tid & 3) * 4;   // A k sub-offset {0,4,8,12}
  const int bk  = tid >> 5;        // B k row 0..15
  const int bn  = (tid & 31) * 8;  // B n offset

  const float* Aptr = F + (size_t)(RM + ar) * Dk + akq;

  float4 av, bv0, bv1, gv;
  av  = *reinterpret_cast<const float4*>(Aptr);
  bv0 = *reinterpret_cast<const float4*>(W1 + (size_t)bk * Hk + bn);
  bv1 = *reinterpret_cast<const float4*>(W1 + (size_t)bk * Hk + bn + 4);
  gv  = *reinterpret_cast<const float4*>(gamma + akq);

  float acc[8][8];
  #pragma unroll
  for (int i = 0; i < 8; ++i)
    #pragma unroll
    for (int j = 0; j < 8; ++j) acc[i][j] = 0.f;

  float rsum = 0.f, rsq = 0.f;

  for (int s = 0; s < Dk / 16; ++s) {
    __syncthreads();  // previous compute done reading LDS
    // row stats on RAW values, then gamma-scale into LDS
    rsum += av.x + av.y + av.z + av.w;
    rsq = fmaf(av.x, av.x, fmaf(av.y, av.y, fmaf(av.z, av.z, fmaf(av.w, av.w, rsq))));
    As[akq + 0][ar] = av.x * gv.x;
    As[akq + 1][ar] = av.y * gv.y;
    As[akq + 2][ar] = av.z * gv.z;
    As[akq + 3][ar] = av.w * gv.w;
    *reinterpret_cast<float4*>(&Bs[bk][bn])     = bv0;
    *reinterpret_cast<float4*>(&Bs[bk][bn + 4]) = bv1;
    __syncthreads();
    if (s + 1 < Dk / 16) {  // register double-buffer: prefetch next tile
      av  = *reinterpret_cast<const float4*>(Aptr + (s + 1) * 16);
      bv0 = *reinterpret_cast<const float4*>(W1 + (size_t)((s + 1) * 16 + bk) * Hk + bn);
      bv1 = *reinterpret_cast<const float4*>(W1 + (size_t)((s + 1) * 16 + bk) * Hk + bn + 4);
      gv  = *reinterpret_cast<const float4*>(gamma + (s + 1) * 16 + akq);
    }
    #pragma unroll
    for (int kk = 0; kk < 16; ++kk) {
      float4 a0 = *reinterpret_cast<const float4*>(&As[kk][ty * 4]);
      float4 a1 = *reinterpret_cast<const float4*>(&As[kk][ty * 4 + 64]);
      float4 b0 = *reinterpret_cast<const float4*>(&Bs[kk][tx * 4]);
      float4 b1 = *reinterpret_cast<const float4*>(&Bs[kk][tx * 4 + 128]);
      float a[8]  = {a0.x, a0.y, a0.z, a0.w, a1.x, a1.y, a1.z, a1.w};
      float bb[8] = {b0.x, b0.y, b0.z, b0.w, b1.x, b1.y, b1.z, b1.w};
      #pragma unroll
      for (int i = 0; i < 8; ++i)
        #pragma unroll
        for (int j = 0; j < 8; ++j)
          acc[i][j] = fmaf(a[i], bb[j], acc[i][j]);
    }
  }

  // finish row stats: threads 4r..4r+3 each hold a quarter of row r
  rsum += __shfl_xor(rsum, 1); rsum += __shfl_xor(rsum, 2);
  rsq  += __shfl_xor(rsq, 1);  rsq  += __shfl_xor(rsq, 2);
  if ((tid & 3) == 0) {
    float mu  = rsum * (1.f / 1024.f);
    float var = rsq * (1.f / 1024.f) - mu * mu;
    smu[ar] = mu;
    srs[ar] = rsqrtf(var + 1e-5f);
  }
  __syncthreads();

  // epilogue: LN affine + GELU(exact) + dot with W2, half-wave reduce over n
  float sj[8], tbj[8], w2j[8];
  #pragma unroll
  for (int j = 0; j < 8; ++j) {
    int nj = tx * 4 + (j < 4 ? j : 124 + j);
    sj[j] = S[nj]; tbj[j] = Tb[nj]; w2j[j] = W2[nj];
  }
  const float bias2 = b2[0];
  #pragma unroll
  for (int i = 0; i < 8; ++i) {
    int mi = ty * 4 + (i < 4 ? i : 60 + i);
    float mu = smu[mi], rs = srs[mi];
    float part = 0.f;
    #pragma unroll
    for (int j = 0; j < 8; ++j) {
      float hpre = rs * acc[i][j] - rs * mu * sj[j] + tbj[j];
      float h = 0.5f * hpre * (1.f + erff(hpre * 0.70710678118654752f));
      part = fmaf(h, w2j[j], part);
    }
    #pragma unroll
    for (int off = 1; off < 32; off <<= 1) part += __shfl_xor(part, off);
    if (tx == 0) scores_out[RM + mi] = part + bias2;
  }
}

// ---------------- topk: per-batch full bitonic sort of (descending score, ascending idx)
__global__ __launch_bounds__(1024) void topk_kernel(
    const float* __restrict__ scores, int k,
    float* __restrict__ idx_f, int* __restrict__ idx_i) {
  __shared__ unsigned long long keys[Lk];  // 64 KB
  const int b = blockIdx.x, t = threadIdx.x;
  for (int i = t; i < Lk; i += 1024) {
    unsigned u = __float_as_uint(scores[(size_t)b * Lk + i]);
    unsigned mono = (u & 0x80000000u) ? ~u : (u | 0x80000000u);  // ascending in value
    keys[i] = ((unsigned long long)(~mono) << 32) | (unsigned)i; // asc sort => desc score, asc idx
  }
  __syncthreads();
  for (int size = 2; size <= Lk; size <<= 1) {
    for (int stride = size >> 1; stride > 0; stride >>= 1) {
      for (int p = t; p < Lk / 2; p += 1024) {
        int lo = ((p & ~(stride - 1)) << 1) | (p & (stride - 1));
        int hi = lo + stride;
        bool up = ((lo & size) == 0);
        unsigned long long a = keys[lo], c = keys[hi];
        if ((a > c) == up) { keys[lo] = c; keys[hi] = a; }
      }
      __syncthreads();
    }
  }
  for (int i = t; i < k; i += 1024) {
    int id = (int)(keys[i] & 0xFFFFFFFFu);
    idx_f[(size_t)b * k + i] = (float)id;  // out buffer is fp32; indices exact in fp32
    idx_i[(size_t)b * k + i] = id;
  }
}

// ---------------- gather: one block per selected row, 4 KB float4 copy
__global__ __launch_bounds__(256) void gather_kernel(
    const float* __restrict__ F, const int* __restrict__ idx,
    float* __restrict__ out, int k) {
  int row = blockIdx.x;          // 0 .. 8*k-1
  int b = row / k;
  int id = idx[row];
  const float4* src = reinterpret_cast<const float4*>(F + ((size_t)b * Lk + id) * Dk);
  float4* dst = reinterpret_cast<float4*>(out + (size_t)row * Dk);
  dst[threadIdx.x] = src[threadIdx.x];
}

extern "C" void kernel_launch(void* const* d_in, const int* in_sizes, int n_in,
                              void* d_out, int out_size, void* d_ws, size_t ws_size,
                              hipStream_t stream) {
  const float* F     = (const float*)d_in[0];
  const float* gamma = (const float*)d_in[1];
  const float* beta  = (const float*)d_in[2];
  const float* W1    = (const float*)d_in[3];
  const float* b1    = (const float*)d_in[4];
  const float* W2    = (const float*)d_in[5];
  const float* b2    = (const float*)d_in[6];
  // k lives on device; derive on host from out_size = 8*k*1024 + 8*8192 + 8*k
  int k = (out_size - Bk * Lk) / (Bk * Dk + Bk);   // = 512

  float* out_sel = (float*)d_out;                       // [8, k, 1024]
  float* out_sc  = out_sel + (size_t)Bk * k * Dk;       // [8, 8192]
  float* out_idx = out_sc + (size_t)Bk * Lk;            // [8, k] as float

  float* S    = (float*)d_ws;
  float* Tb   = S + Hk;
  int*   idxi = (int*)(Tb + Hk);

  hipLaunchKernelGGL(prep_kernel,   dim3(1),         dim3(Hk),  0, stream,
                     gamma, beta, W1, b1, S, Tb);
  hipLaunchKernelGGL(scores_kernel, dim3(MTOT / 128), dim3(512), 0, stream,
                     F, gamma, W1, S, Tb, W2, b2, out_sc);
  hipLaunchKernelGGL(topk_kernel,   dim3(Bk),        dim3(1024), 0, stream,
                     out_sc, k, out_idx, idxi);
  hipLaunchKernelGGL(gather_kernel, dim3(Bk * k),    dim3(256), 0, stream,
                     F, idxi, out_sel, k);
}